// Round 1
// baseline (37.882 us; speedup 1.0000x reference)
//
#include <hip/hip_runtime.h>

#define TPB 256

__global__ __launch_bounds__(TPB) void brownian_so3_kernel(
    const float* __restrict__ x0,
    const float* __restrict__ t,
    const float* __restrict__ noise,
    float* __restrict__ out,
    int B, int steps)
{
    // Two staging buffers (double-buffered noise tiles) of 256*9 floats each.
    __shared__ float lds[2][TPB * 9];

    const int tid  = threadIdx.x;
    const int blk  = blockIdx.x;
    const long base = (long)blk * TPB * 9;   // float offset of this block's tile
    const int b    = blk * TPB + tid;        // sample index

    // ---- Stage x0 tile via coalesced float4 loads ----
    {
        const float4* src = (const float4*)(x0 + base);
        float4* dst = (float4*)lds[0];
        dst[tid]        = src[tid];
        dst[tid + TPB]  = src[tid + TPB];
        if (tid < 64) dst[tid + 2*TPB] = src[tid + 2*TPB];   // 576 float4 total
    }
    __syncthreads();

    float x[9];
    #pragma unroll
    for (int j = 0; j < 9; ++j) x[j] = lds[0][tid*9 + j];
    __syncthreads();   // buffer 0 will be overwritten by step 0's noise

    const float sd = sqrtf(t[b] / (float)steps);   // sqrt(dt) per sample
    const float hs = 0.5f * sd;

    // ---- Prefetch step-0 noise tile into registers ----
    float4 r0, r1, r2 = make_float4(0.f, 0.f, 0.f, 0.f);
    {
        const float4* src = (const float4*)(noise + base);
        r0 = src[tid];
        r1 = src[tid + TPB];
        if (tid < 64) r2 = src[tid + 2*TPB];
    }

    for (int s = 0; s < steps; ++s) {
        float* buf = lds[s & 1];
        {
            float4* dst = (float4*)buf;
            dst[tid]       = r0;
            dst[tid + TPB] = r1;
            if (tid < 64) dst[tid + 2*TPB] = r2;
        }
        __syncthreads();

        // Prefetch next step's tile (overlaps with compute below).
        if (s + 1 < steps) {
            const float4* src = (const float4*)(noise + (long)(s+1) * B * 9 + base);
            r0 = src[tid];
            r1 = src[tid + TPB];
            if (tid < 64) r2 = src[tid + 2*TPB];
        }

        float e[9];
        #pragma unroll
        for (int j = 0; j < 9; ++j) e[j] = buf[tid*9 + j];

        // S = 0.5*sd*(x^T e - e^T x), axial vector (a,b,c):
        //   a = S21, b = S02, c = S10
        float wa = 0.f, wb = 0.f, wc = 0.f;
        #pragma unroll
        for (int k = 0; k < 3; ++k) {
            const float xk0 = x[k*3+0], xk1 = x[k*3+1], xk2 = x[k*3+2];
            const float ek0 = e[k*3+0], ek1 = e[k*3+1], ek2 = e[k*3+2];
            wa += xk2*ek1 - xk1*ek2;
            wb += xk0*ek2 - xk2*ek0;
            wc += xk1*ek0 - xk0*ek1;
        }
        const float A  = hs * wa;
        const float Bv = hs * wb;
        const float Cv = hs * wc;

        const float th2 = A*A + Bv*Bv + Cv*Cv;
        const float c1  = rsqrtf(1.0f + th2);
        const float c2  = c1*c1 / (1.0f + c1);     // (1-c1)/th2, stable at th2->0

        // Q = I + c1*S + c2*S^2  (Rodrigues closed-form polar factor of I+S)
        const float q00 = 1.0f - c2*(Bv*Bv + Cv*Cv);
        const float q11 = 1.0f - c2*(A*A  + Cv*Cv);
        const float q22 = 1.0f - c2*(A*A  + Bv*Bv);
        const float q01 = c2*A*Bv  - c1*Cv;
        const float q10 = c2*A*Bv  + c1*Cv;
        const float q02 = c2*A*Cv  + c1*Bv;
        const float q20 = c2*A*Cv  - c1*Bv;
        const float q12 = c2*Bv*Cv - c1*A;
        const float q21 = c2*Bv*Cv + c1*A;

        // x <- x * Q
        #pragma unroll
        for (int r = 0; r < 3; ++r) {
            const float a0 = x[r*3+0], a1 = x[r*3+1], a2 = x[r*3+2];
            x[r*3+0] = a0*q00 + a1*q10 + a2*q20;
            x[r*3+1] = a0*q01 + a1*q11 + a2*q21;
            x[r*3+2] = a0*q02 + a1*q12 + a2*q22;
        }

        __syncthreads();   // safe to overwrite buf[(s+1)&1] next iteration
    }

    // ---- Stage result through LDS for coalesced float4 stores ----
    float* obuf = lds[0];
    #pragma unroll
    for (int j = 0; j < 9; ++j) obuf[tid*9 + j] = x[j];
    __syncthreads();
    {
        float4* dst = (float4*)(out + base);
        const float4* src = (const float4*)obuf;
        dst[tid]       = src[tid];
        dst[tid + TPB] = src[tid + TPB];
        if (tid < 64) dst[tid + 2*TPB] = src[tid + 2*TPB];
    }
}

extern "C" void kernel_launch(void* const* d_in, const int* in_sizes, int n_in,
                              void* d_out, int out_size, void* d_ws, size_t ws_size,
                              hipStream_t stream) {
    const float* x0    = (const float*)d_in[0];
    const float* t     = (const float*)d_in[1];
    const float* noise = (const float*)d_in[2];
    float* out = (float*)d_out;

    const int B     = in_sizes[0] / 9;
    const int steps = in_sizes[2] / in_sizes[0];

    const int grid = B / TPB;   // B = 262144 -> 1024 blocks
    brownian_so3_kernel<<<grid, TPB, 0, stream>>>(x0, t, noise, out, B, steps);
}